// Round 8
// baseline (165.954 us; speedup 1.0000x reference)
//
#include <hip/hip_runtime.h>
#include <hip/hip_bf16.h>
#include <math.h>

// Problem geometry (B=2, T=1024, D=384 -> d=128, D3=384, D9=1152)
#define NTOK  2048
#define DD    128
#define DD3   384
#define DD9   1152
#define TB    2          // tokens per block -> 1024 blocks = 4/CU
#define GAMMA_F 5.0f
#define LN2_F   0.69314718f
#define LOG2E_F 1.44269504f

// Workspace layout (float units):
//  OFF_M  : Mq,Mk,Mv  (3 x 128x384 fp32)   M[i][m] = sum_j softplus(W[j][i]) * S[j][m]
//  OFF_C  : cq,ck,cv  (3 x 384 fp32)       c[m]    = sum_j b[j] * S[j][m]
//  OFF_WP2: delta-packed bf16 Wp (384x384 uint2): [i][m] = {lo:d0,hi:d1},{lo:d2}
//           d_r = bf16(softplus(Wp[r*384+m][i]) - ln2)
#define OFF_M    0
#define OFF_C    147456
#define OFF_WP2  148608   // 147456 uint2 = 294912 floats

typedef __attribute__((ext_vector_type(2))) float f32x2;

__device__ __forceinline__ float softplusf(float x) {
    return fmaxf(x, 0.0f) + log1pf(__expf(-fabsf(x)));   // stable log1p(exp(x))
}
__device__ __forceinline__ unsigned short f2bf(float f) {
    __hip_bfloat16 h = __float2bfloat16(f);              // RNE
    return *reinterpret_cast<unsigned short*>(&h);
}
__device__ __forceinline__ float exp2_fast(float x) {
#if __has_builtin(__builtin_amdgcn_exp2f)
    return __builtin_amdgcn_exp2f(x);
#else
    return __expf(x * LN2_F);
#endif
}

// ---------------- merged prep: grid 771 x 384 (verbatim from round-5/7 pass)
__global__ __launch_bounds__(384) void k_prep(const float* __restrict__ Wq, const float* __restrict__ Wk,
                                              const float* __restrict__ Wv, const float* __restrict__ Wp,
                                              const float* __restrict__ Sq, const float* __restrict__ Sk,
                                              const float* __restrict__ Sv, const float* __restrict__ bq,
                                              const float* __restrict__ bk, const float* __restrict__ bv,
                                              float* __restrict__ ws) {
    __shared__ float sw[DD3];
    int b = blockIdx.x, tid = threadIdx.x;
    if (b < 384) {                       // ---- Wp pack: idx in [0,147456)
        int idx = b * 384 + tid;
        int i = idx / DD3, m = idx % DD3;
        unsigned d0 = f2bf(softplusf(Wp[(0 * DD3 + m) * DD3 + i]) - LN2_F);
        unsigned d1 = f2bf(softplusf(Wp[(1 * DD3 + m) * DD3 + i]) - LN2_F);
        unsigned d2 = f2bf(softplusf(Wp[(2 * DD3 + m) * DD3 + i]) - LN2_F);
        uint2 u; u.x = d0 | (d1 << 16); u.y = d2;
        ((uint2*)(ws + OFF_WP2))[idx] = u;
    } else if (b < 768) {                // ---- M[i][m] for one (mat, i)
        int bb = b - 384;
        int mat = bb >> 7, i = bb & 127;
        const float* W = (mat == 0) ? Wq : (mat == 1 ? Wk : Wv);
        const float* S = (mat == 0) ? Sq : (mat == 1 ? Sk : Sv);
        int m = tid;
        sw[m] = softplusf(W[m * DD + i]);                // j = tid
        __syncthreads();
        const float4* sw4 = (const float4*)sw;
        float a0 = 0.f, a1 = 0.f, a2 = 0.f, a3 = 0.f;
        for (int j4 = 0; j4 < 96; ++j4) {
            float4 w = sw4[j4];
            int j = j4 * 4;
            a0 = fmaf(w.x, S[(j + 0) * DD3 + m], a0);
            a1 = fmaf(w.y, S[(j + 1) * DD3 + m], a1);
            a2 = fmaf(w.z, S[(j + 2) * DD3 + m], a2);
            a3 = fmaf(w.w, S[(j + 3) * DD3 + m], a3);
        }
        ws[OFF_M + mat * 49152 + i * DD3 + m] = (a0 + a1) + (a2 + a3);
    } else {                             // ---- c[m]
        int mat = b - 768;
        const float* S = (mat == 0) ? Sq : (mat == 1 ? Sk : Sv);
        const float* bb_ = (mat == 0) ? bq : (mat == 1 ? bk : bv);
        int m = tid;
        float a0 = 0.f, a1 = 0.f, a2 = 0.f, a3 = 0.f;
        for (int j4 = 0; j4 < 96; ++j4) {
            int j = j4 * 4;
            a0 = fmaf(bb_[j + 0], S[(j + 0) * DD3 + m], a0);
            a1 = fmaf(bb_[j + 1], S[(j + 1) * DD3 + m], a1);
            a2 = fmaf(bb_[j + 2], S[(j + 2) * DD3 + m], a2);
            a3 = fmaf(bb_[j + 3], S[(j + 3) * DD3 + m], a3);
        }
        ws[OFF_C + mat * DD3 + m] = (a0 + a1) + (a2 + a3);
    }
}

// Packed sigmoid row-quad: 4 elems of one row. 5 trans (4 exp + 1 group-rcp)
// instead of 8; pk_f32 for all pairable ops. y clamped at 30 so the w-product
// stays finite (s error from clamp <= 2^-30, negligible).
#define SIGROW4(NQ2, RS2, AV2) do {                                         \
        f32x2 ya = __builtin_elementwise_min((NQ2) * kxy, CLAMP2);          \
        f32x2 yb = __builtin_elementwise_min((NQ2) * kzw, CLAMP2);          \
        f32x2 wa = (f32x2){exp2_fast(ya.x), exp2_fast(ya.y)} + ONE2;        \
        f32x2 wb = (f32x2){exp2_fast(yb.x), exp2_fast(yb.y)} + ONE2;        \
        float p01 = wa.x * wa.y;                                            \
        float p23 = wb.x * wb.y;                                            \
        float rp  = __builtin_amdgcn_rcpf(p01 * p23);                       \
        float q01 = rp * p23;                                               \
        float q23 = rp * p01;                                               \
        f32x2 sa = (f32x2){q01, q01} * (f32x2){wa.y, wa.x};                 \
        f32x2 sb = (f32x2){q23, q23} * (f32x2){wb.y, wb.x};                 \
        RS2 = RS2 + sa + sb;                                                \
        AV2 = __builtin_elementwise_fma(sa, vxy, AV2);                      \
        AV2 = __builtin_elementwise_fma(sb, vzw, AV2);                      \
    } while (0)

// ---------------- fused main (TB=2)
__global__ __launch_bounds__(384, 6) void k_fused(const float* __restrict__ x,
                                                  const float* __restrict__ bp,
                                                  const float* __restrict__ gn,
                                                  const float* __restrict__ bn,
                                                  const float* __restrict__ ws,
                                                  float* __restrict__ out) {
    __shared__ float qkv[3 * TB * DD3];     // 9 KB  (Q | K | V, each [TB][384])
    __shared__ float att[TB * DD3];         // 3 KB
    __shared__ float red[16];
    __shared__ float ssum[TB], smu[TB], sinv[TB];

    int tid = threadIdx.x;                  // 0..383
    int tok0 = blockIdx.x * TB;
    const float* xb = x + (size_t)tok0 * DD3;

    // ---- phase 2: QKV projection. x via wave-uniform (scalar) global loads.
#pragma unroll
    for (int mat = 0; mat < 3; ++mat) {
        const float* M = ws + OFF_M + mat * 49152;
        const float* xt0 = xb + 0 * DD3 + mat * DD;
        const float* xt1 = xb + 1 * DD3 + mat * DD;
        float a0 = 0.f, a1 = 0.f;
        for (int i = 0; i < DD; i += 4) {
            float m0 = M[(i + 0) * DD3 + tid];
            float m1 = M[(i + 1) * DD3 + tid];
            float m2 = M[(i + 2) * DD3 + tid];
            float m3 = M[(i + 3) * DD3 + tid];
            a0 = fmaf(xt0[i], m0, fmaf(xt0[i + 1], m1, fmaf(xt0[i + 2], m2, fmaf(xt0[i + 3], m3, a0))));
            a1 = fmaf(xt1[i], m0, fmaf(xt1[i + 1], m1, fmaf(xt1[i + 2], m2, fmaf(xt1[i + 3], m3, a1))));
        }
        float c = ws[OFF_C + mat * DD3 + tid];
        qkv[(mat * TB + 0) * DD3 + tid] = a0 + c;
        qkv[(mat * TB + 1) * DD3 + tid] = a1 + c;
    }
    __syncthreads();

    // ---- phase 3: sigmoid attention. Thread owns rows {ts, ts+192} of ONE token.
    {
        int t  = tid / 192;                 // wave-uniform (192 = 3 waves)
        int ts = tid - t * 192;
        const float* Qt = qkv + t * DD3;
        float nq0 = Qt[ts]       * (-GAMMA_F * LOG2E_F);
        float nq1 = Qt[ts + 192] * (-GAMMA_F * LOG2E_F);
        f32x2 nq02 = (f32x2){nq0, nq0};
        f32x2 nq12 = (f32x2){nq1, nq1};
        const f32x2 CLAMP2 = (f32x2){30.f, 30.f};
        const f32x2 ONE2   = (f32x2){1.f, 1.f};
        const float4* K4 = (const float4*)(qkv + (TB + t) * DD3);
        const float4* V4 = (const float4*)(qkv + (2 * TB + t) * DD3);
        f32x2 rs0 = (f32x2){0.f, 0.f}, rs1 = (f32x2){0.f, 0.f};
        f32x2 av0 = (f32x2){0.f, 0.f}, av1 = (f32x2){0.f, 0.f};
        for (int j4 = 0; j4 < 96; ++j4) {
            float4 kk = K4[j4];
            float4 vv = V4[j4];
            f32x2 kxy = (f32x2){kk.x, kk.y}, kzw = (f32x2){kk.z, kk.w};
            f32x2 vxy = (f32x2){vv.x, vv.y}, vzw = (f32x2){vv.z, vv.w};
            SIGROW4(nq02, rs0, av0);
            SIGROW4(nq12, rs1, av1);
        }
        float rsum0 = rs0.x + rs0.y, rsum1 = rs1.x + rs1.y;
        float avs0  = av0.x + av0.y, avs1  = av1.x + av1.y;
        att[t * DD3 + ts]       = avs0 * __builtin_amdgcn_rcpf(rsum0 + 1e-8f);
        att[t * DD3 + ts + 192] = avs1 * __builtin_amdgcn_rcpf(rsum1 + 1e-8f);
    }
    __syncthreads();

    int wave = tid >> 6, lane64 = tid & 63;

    // ---- per-token sum of att (ln2 rank-1 fold)
    {
        float s0 = att[0 * DD3 + tid];
        float s1 = att[1 * DD3 + tid];
#pragma unroll
        for (int off = 32; off; off >>= 1) {
            s0 += __shfl_down(s0, off, 64);
            s1 += __shfl_down(s1, off, 64);
        }
        if (lane64 == 0) { red[wave] = s0; red[8 + wave] = s1; }
        __syncthreads();
        if (tid < TB) {
            float a = 0.f;
            for (int w = 0; w < 6; ++w) a += red[tid * 8 + w];
            ssum[tid] = a;
        }
        __syncthreads();
    }

    // ---- phase 4: h[t][o] = bp[o] + ln2*ssum[t] + sum_i att[t][i]*delta[i][o]
    const uint2* wp2 = (const uint2*)(ws + OFF_WP2);
    f32x2 acc2[3];
    {
        float bp0 = bp[tid], bp1 = bp[tid + DD3], bp2 = bp[tid + 2 * DD3];
        float b0 = LN2_F * ssum[0], b1 = LN2_F * ssum[1];
        acc2[0] = (f32x2){bp0 + b0, bp0 + b1};
        acc2[1] = (f32x2){bp1 + b0, bp1 + b1};
        acc2[2] = (f32x2){bp2 + b0, bp2 + b1};
    }
    const float4* att4 = (const float4*)att;
    for (int i4 = 0; i4 < 96; ++i4) {
        float4 a0 = att4[0 * 96 + i4];
        float4 a1 = att4[1 * 96 + i4];
        const float* af0 = (const float*)&a0;
        const float* af1 = (const float*)&a1;
#pragma unroll
        for (int e = 0; e < 4; ++e) {
            uint2 u = wp2[(i4 * 4 + e) * DD3 + tid];
            float w0 = __uint_as_float(u.x << 16);
            float w1 = __uint_as_float(u.x & 0xffff0000u);
            float w2 = __uint_as_float(u.y << 16);
            f32x2 a01 = (f32x2){af0[e], af1[e]};
            acc2[0] = __builtin_elementwise_fma(a01, (f32x2){w0, w0}, acc2[0]);
            acc2[1] = __builtin_elementwise_fma(a01, (f32x2){w1, w1}, acc2[1]);
            acc2[2] = __builtin_elementwise_fma(a01, (f32x2){w2, w2}, acc2[2]);
        }
    }
    float av_[3][TB] = {{acc2[0].x, acc2[0].y}, {acc2[1].x, acc2[1].y}, {acc2[2].x, acc2[2].y}};

    // ---- phase 5: two-pass LayerNorm (mu first; then var of deviations)
#pragma unroll
    for (int t = 0; t < TB; ++t) {
        float s = av_[0][t] + av_[1][t] + av_[2][t];
#pragma unroll
        for (int off = 32; off; off >>= 1) s += __shfl_down(s, off, 64);
        if (lane64 == 0) red[t * 8 + wave] = s;
    }
    __syncthreads();
    if (tid < TB) {
        float a = 0.f;
        for (int w = 0; w < 6; ++w) a += red[tid * 8 + w];
        smu[tid] = a * (1.0f / 1152.0f);
    }
    __syncthreads();
#pragma unroll
    for (int t = 0; t < TB; ++t) {
        float mu = smu[t];
        av_[0][t] -= mu; av_[1][t] -= mu; av_[2][t] -= mu;
        float s = fmaf(av_[0][t], av_[0][t], fmaf(av_[1][t], av_[1][t], av_[2][t] * av_[2][t]));
#pragma unroll
        for (int off = 32; off; off >>= 1) s += __shfl_down(s, off, 64);
        if (lane64 == 0) red[t * 8 + wave] = s;
    }
    __syncthreads();
    if (tid < TB) {
        float b = 0.f;
        for (int w = 0; w < 6; ++w) b += red[tid * 8 + w];
        sinv[tid] = __builtin_amdgcn_rsqf(b * (1.0f / 1152.0f) + 1e-5f);
    }
    __syncthreads();
    float g0 = gn[tid], g1 = gn[tid + DD3], g2 = gn[tid + 2 * DD3];
    float b0 = bn[tid], b1 = bn[tid + DD3], b2 = bn[tid + 2 * DD3];
#pragma unroll
    for (int t = 0; t < TB; ++t) {
        float inv = sinv[t];
        size_t base = (size_t)(tok0 + t) * DD9;
        out[base + tid]           = fmaf(av_[0][t] * inv, g0, b0);
        out[base + tid + DD3]     = fmaf(av_[1][t] * inv, g1, b1);
        out[base + tid + 2 * DD3] = fmaf(av_[2][t] * inv, g2, b2);
    }
}

extern "C" void kernel_launch(void* const* d_in, const int* in_sizes, int n_in,
                              void* d_out, int out_size, void* d_ws, size_t ws_size,
                              hipStream_t stream) {
    const float* x  = (const float*)d_in[0];
    const float* Wq = (const float*)d_in[1];
    const float* bq = (const float*)d_in[2];
    const float* Sq = (const float*)d_in[3];
    const float* Wk = (const float*)d_in[4];
    const float* bk = (const float*)d_in[5];
    const float* Sk = (const float*)d_in[6];
    const float* Wv = (const float*)d_in[7];
    const float* bv = (const float*)d_in[8];
    const float* Sv = (const float*)d_in[9];
    const float* Wp = (const float*)d_in[10];
    const float* bp = (const float*)d_in[11];
    const float* gn = (const float*)d_in[12];
    const float* bn = (const float*)d_in[13];
    float* out = (float*)d_out;
    float* ws  = (float*)d_ws;

    hipLaunchKernelGGL(k_prep, dim3(771), dim3(384), 0, stream,
                       Wq, Wk, Wv, Wp, Sq, Sk, Sv, bq, bk, bv, ws);
    hipLaunchKernelGGL(k_fused, dim3(NTOK / TB), dim3(384), 0, stream, x, bp, gn, bn, ws, out);
}

// Round 10
// 156.561 us; speedup vs baseline: 1.0600x; 1.0600x over previous
//
#include <hip/hip_runtime.h>
#include <hip/hip_bf16.h>
#include <math.h>

// Problem geometry (B=2, T=1024, D=384 -> d=128, D3=384, D9=1152)
#define NTOK  2048
#define DD    128
#define DD3   384
#define DD9   1152
#define TB    2          // tokens per block -> 1024 blocks = 4/CU
#define GAMMA_F 5.0f
#define LN2_F   0.69314718f
#define LOG2E_F 1.44269504f

// Workspace layout (float units):
//  OFF_M  : Mq,Mk,Mv interleaved-by-4 (3 x 32x384 float4):
//           M4[mat][i>>2][m] = {M[i][m], M[i+1][m], M[i+2][m], M[i+3][m]}
//  OFF_C  : cq,ck,cv  (3 x 384 fp32)
//  OFF_WP2: delta bf16 Wp, k-PAIR packed as uint4[(i>>1)*384 + m]:
//           {lo: d0(i0)|d1(i0)<<16, d2(i0), d0(i1)|d1(i1)<<16, d2(i1)}
//           d_r = bf16(softplus(Wp[r*384+m][i]) - ln2)
#define OFF_M    0
#define OFF_C    147456
#define OFF_WP2  148608   // 73728 uint4 = 294912 floats

typedef __attribute__((ext_vector_type(2))) float f32x2;

__device__ __forceinline__ float softplusf(float x) {
    return fmaxf(x, 0.0f) + log1pf(__expf(-fabsf(x)));   // stable log1p(exp(x))
}
__device__ __forceinline__ unsigned short f2bf(float f) {
    __hip_bfloat16 h = __float2bfloat16(f);              // RNE
    return *reinterpret_cast<unsigned short*>(&h);
}
__device__ __forceinline__ float exp2_fast(float x) {
#if __has_builtin(__builtin_amdgcn_exp2f)
    return __builtin_amdgcn_exp2f(x);
#else
    return __expf(x * LN2_F);
#endif
}

// ---------------- merged prep: grid 771 x 384
//  [0,384)   : Wp delta-pack (i = blockIdx, m = tid) -> k-pair uint4 layout
//  [384,768) : M matrices -> interleaved-by-4 layout
//  [768,771) : c vectors
__global__ __launch_bounds__(384) void k_prep(const float* __restrict__ Wq, const float* __restrict__ Wk,
                                              const float* __restrict__ Wv, const float* __restrict__ Wp,
                                              const float* __restrict__ Sq, const float* __restrict__ Sk,
                                              const float* __restrict__ Sv, const float* __restrict__ bq,
                                              const float* __restrict__ bk, const float* __restrict__ bv,
                                              float* __restrict__ ws) {
    __shared__ float sw[DD3];
    int b = blockIdx.x, tid = threadIdx.x;
    if (b < 384) {                       // ---- Wp pack: i = b, m = tid
        int i = b, m = tid;
        unsigned d0 = f2bf(softplusf(Wp[(0 * DD3 + m) * DD3 + i]) - LN2_F);
        unsigned d1 = f2bf(softplusf(Wp[(1 * DD3 + m) * DD3 + i]) - LN2_F);
        unsigned d2 = f2bf(softplusf(Wp[(2 * DD3 + m) * DD3 + i]) - LN2_F);
        unsigned* base = (unsigned*)(ws + OFF_WP2);
        int idx = (i >> 1) * (DD3 * 4) + m * 4 + (i & 1) * 2;   // 8B-aligned half of uint4
        uint2 u; u.x = d0 | (d1 << 16); u.y = d2;
        *(uint2*)(base + idx) = u;
    } else if (b < 768) {                // ---- M[i][m] for one (mat, i), interleaved store
        int bb = b - 384;
        int mat = bb >> 7, i = bb & 127;
        const float* W = (mat == 0) ? Wq : (mat == 1 ? Wk : Wv);
        const float* S = (mat == 0) ? Sq : (mat == 1 ? Sk : Sv);
        int m = tid;
        sw[m] = softplusf(W[m * DD + i]);                // j = tid
        __syncthreads();
        const float4* sw4 = (const float4*)sw;
        float a0 = 0.f, a1 = 0.f, a2 = 0.f, a3 = 0.f;
        for (int j4 = 0; j4 < 96; ++j4) {
            float4 w = sw4[j4];
            int j = j4 * 4;
            a0 = fmaf(w.x, S[(j + 0) * DD3 + m], a0);
            a1 = fmaf(w.y, S[(j + 1) * DD3 + m], a1);
            a2 = fmaf(w.z, S[(j + 2) * DD3 + m], a2);
            a3 = fmaf(w.w, S[(j + 3) * DD3 + m], a3);
        }
        ws[OFF_M + mat * 49152 + (i >> 2) * (DD3 * 4) + m * 4 + (i & 3)] = (a0 + a1) + (a2 + a3);
    } else {                             // ---- c[m]
        int mat = b - 768;
        const float* S = (mat == 0) ? Sq : (mat == 1 ? Sk : Sv);
        const float* bb_ = (mat == 0) ? bq : (mat == 1 ? bk : bv);
        int m = tid;
        float a0 = 0.f, a1 = 0.f, a2 = 0.f, a3 = 0.f;
        for (int j4 = 0; j4 < 96; ++j4) {
            int j = j4 * 4;
            a0 = fmaf(bb_[j + 0], S[(j + 0) * DD3 + m], a0);
            a1 = fmaf(bb_[j + 1], S[(j + 1) * DD3 + m], a1);
            a2 = fmaf(bb_[j + 2], S[(j + 2) * DD3 + m], a2);
            a3 = fmaf(bb_[j + 3], S[(j + 3) * DD3 + m], a3);
        }
        ws[OFF_C + mat * DD3 + m] = (a0 + a1) + (a2 + a3);
    }
}

// Scalar sigmoid quad (round-7 proven form): 4 exp2 + 4 rcp.
#define SIGROW(NQ, RS, AV) do {                                        \
        float e0 = exp2_fast((NQ) * kk.x);                             \
        float e1 = exp2_fast((NQ) * kk.y);                             \
        float e2 = exp2_fast((NQ) * kk.z);                             \
        float e3 = exp2_fast((NQ) * kk.w);                             \
        float s0 = __builtin_amdgcn_rcpf(1.0f + e0);                   \
        float s1 = __builtin_amdgcn_rcpf(1.0f + e1);                   \
        float s2 = __builtin_amdgcn_rcpf(1.0f + e2);                   \
        float s3 = __builtin_amdgcn_rcpf(1.0f + e3);                   \
        RS += (s0 + s1) + (s2 + s3);                                   \
        AV = fmaf(s0, vv.x, fmaf(s1, vv.y, fmaf(s2, vv.z, fmaf(s3, vv.w, AV)))); \
    } while (0)

// ---------------- fused main (TB=2)
__global__ __launch_bounds__(384, 6) void k_fused(const float* __restrict__ x,
                                                  const float* __restrict__ bp,
                                                  const float* __restrict__ gn,
                                                  const float* __restrict__ bn,
                                                  const float* __restrict__ ws,
                                                  float* __restrict__ out) {
    __shared__ float qkv[3 * TB * DD3];     // 9 KB  (Q | K | V, each [TB][384])
    __shared__ float att[TB * DD3];         // 3 KB
    __shared__ float red[16];
    __shared__ float ssum[TB], smu[TB], sinv[TB];

    int tid = threadIdx.x;                  // 0..383
    int tok0 = blockIdx.x * TB;
    const float* xb = x + (size_t)tok0 * DD3;

    // ---- phase 2: QKV projection. x via wave-uniform loads; M via one float4/4k.
#pragma unroll
    for (int mat = 0; mat < 3; ++mat) {
        const float4* M4 = (const float4*)(ws + OFF_M + mat * 49152);
        const float* xt0 = xb + 0 * DD3 + mat * DD;
        const float* xt1 = xb + 1 * DD3 + mat * DD;
        float a0 = 0.f, a1 = 0.f;
        for (int i4 = 0; i4 < 32; ++i4) {
            float4 mm = M4[i4 * DD3 + tid];
            int i = i4 * 4;
            a0 = fmaf(xt0[i], mm.x, fmaf(xt0[i + 1], mm.y, fmaf(xt0[i + 2], mm.z, fmaf(xt0[i + 3], mm.w, a0))));
            a1 = fmaf(xt1[i], mm.x, fmaf(xt1[i + 1], mm.y, fmaf(xt1[i + 2], mm.z, fmaf(xt1[i + 3], mm.w, a1))));
        }
        float c = ws[OFF_C + mat * DD3 + tid];
        qkv[(mat * TB + 0) * DD3 + tid] = a0 + c;
        qkv[(mat * TB + 1) * DD3 + tid] = a1 + c;
    }
    __syncthreads();

    // ---- phase 3: sigmoid attention. Thread owns rows {ts, ts+192} of ONE token.
    {
        int t  = tid / 192;                 // wave-uniform (192 = 3 waves)
        int ts = tid - t * 192;
        const float* Qt = qkv + t * DD3;
        float nq0 = Qt[ts]       * (-GAMMA_F * LOG2E_F);
        float nq1 = Qt[ts + 192] * (-GAMMA_F * LOG2E_F);
        const float4* K4 = (const float4*)(qkv + (TB + t) * DD3);
        const float4* V4 = (const float4*)(qkv + (2 * TB + t) * DD3);
        float rs0 = 0.f, rs1 = 0.f, av0 = 0.f, av1 = 0.f;
#pragma unroll 2
        for (int j4 = 0; j4 < 96; ++j4) {
            float4 kk = K4[j4];
            float4 vv = V4[j4];
            SIGROW(nq0, rs0, av0);
            SIGROW(nq1, rs1, av1);
        }
        att[t * DD3 + ts]       = av0 * __builtin_amdgcn_rcpf(rs0 + 1e-8f);
        att[t * DD3 + ts + 192] = av1 * __builtin_amdgcn_rcpf(rs1 + 1e-8f);
    }
    __syncthreads();

    int wave = tid >> 6, lane64 = tid & 63;

    // ---- per-token sum of att (ln2 rank-1 fold)
    {
        float s0 = att[0 * DD3 + tid];
        float s1 = att[1 * DD3 + tid];
#pragma unroll
        for (int off = 32; off; off >>= 1) {
            s0 += __shfl_down(s0, off, 64);
            s1 += __shfl_down(s1, off, 64);
        }
        if (lane64 == 0) { red[wave] = s0; red[8 + wave] = s1; }
        __syncthreads();
        if (tid < TB) {
            float a = 0.f;
            for (int w = 0; w < 6; ++w) a += red[tid * 8 + w];
            ssum[tid] = a;
        }
        __syncthreads();
    }

    // ---- phase 4: h[t][o] = bp[o] + ln2*ssum[t] + sum_i att[t][i]*delta[i][o]
    // uint4 = 2 k-slots per load; pk_fma token pairs; FMA order identical to r7.
    const uint4* wp4 = (const uint4*)(ws + OFF_WP2);
    f32x2 acc2[3];
    {
        float bp0 = bp[tid], bp1 = bp[tid + DD3], bp2 = bp[tid + 2 * DD3];
        float b0 = LN2_F * ssum[0], b1 = LN2_F * ssum[1];
        acc2[0] = (f32x2){bp0 + b0, bp0 + b1};
        acc2[1] = (f32x2){bp1 + b0, bp1 + b1};
        acc2[2] = (f32x2){bp2 + b0, bp2 + b1};
    }
    const float4* att4 = (const float4*)att;
    for (int i4 = 0; i4 < 96; ++i4) {
        float4 a0 = att4[0 * 96 + i4];
        float4 a1 = att4[1 * 96 + i4];
        const float* af0 = (const float*)&a0;
        const float* af1 = (const float*)&a1;
#pragma unroll
        for (int e2 = 0; e2 < 2; ++e2) {
            uint4 u = wp4[(i4 * 2 + e2) * DD3 + tid];
            // k-slot 0 (i = i4*4 + e2*2)
            {
                float w0 = __uint_as_float(u.x << 16);
                float w1 = __uint_as_float(u.x & 0xffff0000u);
                float w2 = __uint_as_float(u.y << 16);
                f32x2 a01 = (f32x2){af0[e2 * 2], af1[e2 * 2]};
                acc2[0] = __builtin_elementwise_fma(a01, (f32x2){w0, w0}, acc2[0]);
                acc2[1] = __builtin_elementwise_fma(a01, (f32x2){w1, w1}, acc2[1]);
                acc2[2] = __builtin_elementwise_fma(a01, (f32x2){w2, w2}, acc2[2]);
            }
            // k-slot 1 (i = i4*4 + e2*2 + 1)
            {
                float w0 = __uint_as_float(u.z << 16);
                float w1 = __uint_as_float(u.z & 0xffff0000u);
                float w2 = __uint_as_float(u.w << 16);
                f32x2 a01 = (f32x2){af0[e2 * 2 + 1], af1[e2 * 2 + 1]};
                acc2[0] = __builtin_elementwise_fma(a01, (f32x2){w0, w0}, acc2[0]);
                acc2[1] = __builtin_elementwise_fma(a01, (f32x2){w1, w1}, acc2[1]);
                acc2[2] = __builtin_elementwise_fma(a01, (f32x2){w2, w2}, acc2[2]);
            }
        }
    }
    float av_[3][TB] = {{acc2[0].x, acc2[0].y}, {acc2[1].x, acc2[1].y}, {acc2[2].x, acc2[2].y}};

    // ---- phase 5: two-pass LayerNorm (mu first; then var of deviations)
#pragma unroll
    for (int t = 0; t < TB; ++t) {
        float s = av_[0][t] + av_[1][t] + av_[2][t];
#pragma unroll
        for (int off = 32; off; off >>= 1) s += __shfl_down(s, off, 64);
        if (lane64 == 0) red[t * 8 + wave] = s;
    }
    __syncthreads();
    if (tid < TB) {
        float a = 0.f;
        for (int w = 0; w < 6; ++w) a += red[tid * 8 + w];
        smu[tid] = a * (1.0f / 1152.0f);
    }
    __syncthreads();
#pragma unroll
    for (int t = 0; t < TB; ++t) {
        float mu = smu[t];
        av_[0][t] -= mu; av_[1][t] -= mu; av_[2][t] -= mu;
        float s = fmaf(av_[0][t], av_[0][t], fmaf(av_[1][t], av_[1][t], av_[2][t] * av_[2][t]));
#pragma unroll
        for (int off = 32; off; off >>= 1) s += __shfl_down(s, off, 64);
        if (lane64 == 0) red[t * 8 + wave] = s;
    }
    __syncthreads();
    if (tid < TB) {
        float b = 0.f;
        for (int w = 0; w < 6; ++w) b += red[tid * 8 + w];
        sinv[tid] = __builtin_amdgcn_rsqf(b * (1.0f / 1152.0f) + 1e-5f);
    }
    __syncthreads();
    float g0 = gn[tid], g1 = gn[tid + DD3], g2 = gn[tid + 2 * DD3];
    float b0 = bn[tid], b1 = bn[tid + DD3], b2 = bn[tid + 2 * DD3];
#pragma unroll
    for (int t = 0; t < TB; ++t) {
        float inv = sinv[t];
        size_t base = (size_t)(tok0 + t) * DD9;
        out[base + tid]           = fmaf(av_[0][t] * inv, g0, b0);
        out[base + tid + DD3]     = fmaf(av_[1][t] * inv, g1, b1);
        out[base + tid + 2 * DD3] = fmaf(av_[2][t] * inv, g2, b2);
    }
}

extern "C" void kernel_launch(void* const* d_in, const int* in_sizes, int n_in,
                              void* d_out, int out_size, void* d_ws, size_t ws_size,
                              hipStream_t stream) {
    const float* x  = (const float*)d_in[0];
    const float* Wq = (const float*)d_in[1];
    const float* bq = (const float*)d_in[2];
    const float* Sq = (const float*)d_in[3];
    const float* Wk = (const float*)d_in[4];
    const float* bk = (const float*)d_in[5];
    const float* Sk = (const float*)d_in[6];
    const float* Wv = (const float*)d_in[7];
    const float* bv = (const float*)d_in[8];
    const float* Sv = (const float*)d_in[9];
    const float* Wp = (const float*)d_in[10];
    const float* bp = (const float*)d_in[11];
    const float* gn = (const float*)d_in[12];
    const float* bn = (const float*)d_in[13];
    float* out = (float*)d_out;
    float* ws  = (float*)d_ws;

    hipLaunchKernelGGL(k_prep, dim3(771), dim3(384), 0, stream,
                       Wq, Wk, Wv, Wp, Sq, Sk, Sv, bq, bk, bv, ws);
    hipLaunchKernelGGL(k_fused, dim3(NTOK / TB), dim3(384), 0, stream, x, bp, gn, bn, ws, out);
}

// Round 12
// 156.270 us; speedup vs baseline: 1.0620x; 1.0019x over previous
//
#include <hip/hip_runtime.h>
#include <hip/hip_bf16.h>
#include <math.h>

// Problem geometry (B=2, T=1024, D=384 -> d=128, D3=384, D9=1152)
#define NTOK  2048
#define DD    128
#define DD3   384
#define DD9   1152
#define TB    2          // tokens per block -> 1024 blocks = 4/CU
#define GAMMA_F 5.0f
#define LN2_F   0.69314718f

// Workspace layout (float units):
//  OFF_M  : Mq,Mk,Mv interleaved-by-4 (3 x 32x384 float4)
//  OFF_C  : cq,ck,cv  (3 x 384 fp32)
//  OFF_WP2: delta bf16 Wp, k-PAIR packed as uint4[(i>>1)*384 + m]
#define OFF_M    0
#define OFF_C    147456
#define OFF_WP2  148608   // 73728 uint4 = 294912 floats

typedef __attribute__((ext_vector_type(2))) float f32x2;

__device__ __forceinline__ float softplusf(float x) {
    return fmaxf(x, 0.0f) + log1pf(__expf(-fabsf(x)));   // stable log1p(exp(x))
}
__device__ __forceinline__ unsigned short f2bf(float f) {
    __hip_bfloat16 h = __float2bfloat16(f);              // RNE
    return *reinterpret_cast<unsigned short*>(&h);
}

// ---------------- merged prep: grid 771 x 384 (verbatim from r10 pass)
__global__ __launch_bounds__(384) void k_prep(const float* __restrict__ Wq, const float* __restrict__ Wk,
                                              const float* __restrict__ Wv, const float* __restrict__ Wp,
                                              const float* __restrict__ Sq, const float* __restrict__ Sk,
                                              const float* __restrict__ Sv, const float* __restrict__ bq,
                                              const float* __restrict__ bk, const float* __restrict__ bv,
                                              float* __restrict__ ws) {
    __shared__ float sw[DD3];
    int b = blockIdx.x, tid = threadIdx.x;
    if (b < 384) {                       // ---- Wp pack: i = b, m = tid
        int i = b, m = tid;
        unsigned d0 = f2bf(softplusf(Wp[(0 * DD3 + m) * DD3 + i]) - LN2_F);
        unsigned d1 = f2bf(softplusf(Wp[(1 * DD3 + m) * DD3 + i]) - LN2_F);
        unsigned d2 = f2bf(softplusf(Wp[(2 * DD3 + m) * DD3 + i]) - LN2_F);
        unsigned* base = (unsigned*)(ws + OFF_WP2);
        int idx = (i >> 1) * (DD3 * 4) + m * 4 + (i & 1) * 2;   // 8B-aligned half of uint4
        uint2 u; u.x = d0 | (d1 << 16); u.y = d2;
        *(uint2*)(base + idx) = u;
    } else if (b < 768) {                // ---- M[i][m] for one (mat, i), interleaved store
        int bb = b - 384;
        int mat = bb >> 7, i = bb & 127;
        const float* W = (mat == 0) ? Wq : (mat == 1 ? Wk : Wv);
        const float* S = (mat == 0) ? Sq : (mat == 1 ? Sk : Sv);
        int m = tid;
        sw[m] = softplusf(W[m * DD + i]);                // j = tid
        __syncthreads();
        const float4* sw4 = (const float4*)sw;
        float a0 = 0.f, a1 = 0.f, a2 = 0.f, a3 = 0.f;
        for (int j4 = 0; j4 < 96; ++j4) {
            float4 w = sw4[j4];
            int j = j4 * 4;
            a0 = fmaf(w.x, S[(j + 0) * DD3 + m], a0);
            a1 = fmaf(w.y, S[(j + 1) * DD3 + m], a1);
            a2 = fmaf(w.z, S[(j + 2) * DD3 + m], a2);
            a3 = fmaf(w.w, S[(j + 3) * DD3 + m], a3);
        }
        ws[OFF_M + mat * 49152 + (i >> 2) * (DD3 * 4) + m * 4 + (i & 3)] = (a0 + a1) + (a2 + a3);
    } else {                             // ---- c[m]
        int mat = b - 768;
        const float* S = (mat == 0) ? Sq : (mat == 1 ? Sk : Sv);
        const float* bb_ = (mat == 0) ? bq : (mat == 1 ? bk : bv);
        int m = tid;
        float a0 = 0.f, a1 = 0.f, a2 = 0.f, a3 = 0.f;
        for (int j4 = 0; j4 < 96; ++j4) {
            int j = j4 * 4;
            a0 = fmaf(bb_[j + 0], S[(j + 0) * DD3 + m], a0);
            a1 = fmaf(bb_[j + 1], S[(j + 1) * DD3 + m], a1);
            a2 = fmaf(bb_[j + 2], S[(j + 2) * DD3 + m], a2);
            a3 = fmaf(bb_[j + 3], S[(j + 3) * DD3 + m], a3);
        }
        ws[OFF_C + mat * DD3 + m] = (a0 + a1) + (a2 + a3);
    }
}

// Deg-13 odd Chebyshev-derived tanh(3x) poly, x = clamp((gamma/6)*q*k, +-1):
// sigma(gamma*q*k) = 0.5 + 0.5*tanh(2.5*q*k) = 0.5 + x*R(x^2).
// R coeffs = half of monomialized sum_{m<=6} (-1)^m B_m T_{2m+1}; B_m from the
// exact partial-fraction Chebyshev expansion (hand-verified at 6 points,
// max |dtanh| ~ 9e-4; clamp tail 1-tanh(3) = 0.005 -> sigma err <= 3e-3).
#define PSIG(FQ2, K2, V2, RS2, AV2) do {                                      \
        f32x2 x_ = __builtin_elementwise_min(                                  \
                     __builtin_elementwise_max((FQ2) * (K2), NEG1), POS1);     \
        f32x2 w_ = x_ * x_;                                                    \
        f32x2 p_ = __builtin_elementwise_fma(                                  \
                   __builtin_elementwise_fma(                                  \
                   __builtin_elementwise_fma(                                  \
                   __builtin_elementwise_fma(                                  \
                   __builtin_elementwise_fma(                                  \
                   __builtin_elementwise_fma(PC13, w_, PC11),                  \
                     w_, PC9), w_, PC7), w_, PC5), w_, PC3), w_, PC1);         \
        f32x2 s_ = __builtin_elementwise_fma(x_, p_, HALF2);                   \
        RS2 = RS2 + s_;                                                        \
        AV2 = __builtin_elementwise_fma(s_, (V2), AV2);                        \
    } while (0)

// ---------------- fused main (TB=2)
__global__ __launch_bounds__(384, 6) void k_fused(const float* __restrict__ x,
                                                  const float* __restrict__ bp,
                                                  const float* __restrict__ gn,
                                                  const float* __restrict__ bn,
                                                  const float* __restrict__ ws,
                                                  float* __restrict__ out) {
    __shared__ float qkv[3 * TB * DD3];     // 9 KB  (Q | K | V, each [TB][384])
    __shared__ float att[TB * DD3];         // 3 KB
    __shared__ float red[16];
    __shared__ float ssum[TB], smu[TB], sinv[TB];

    int tid = threadIdx.x;                  // 0..383
    int tok0 = blockIdx.x * TB;
    const float* xb = x + (size_t)tok0 * DD3;

    // ---- phase 2: QKV projection. x via wave-uniform loads; M via one float4/4k.
#pragma unroll
    for (int mat = 0; mat < 3; ++mat) {
        const float4* M4 = (const float4*)(ws + OFF_M + mat * 49152);
        const float* xt0 = xb + 0 * DD3 + mat * DD;
        const float* xt1 = xb + 1 * DD3 + mat * DD;
        float a0 = 0.f, a1 = 0.f;
        for (int i4 = 0; i4 < 32; ++i4) {
            float4 mm = M4[i4 * DD3 + tid];
            int i = i4 * 4;
            a0 = fmaf(xt0[i], mm.x, fmaf(xt0[i + 1], mm.y, fmaf(xt0[i + 2], mm.z, fmaf(xt0[i + 3], mm.w, a0))));
            a1 = fmaf(xt1[i], mm.x, fmaf(xt1[i + 1], mm.y, fmaf(xt1[i + 2], mm.z, fmaf(xt1[i + 3], mm.w, a1))));
        }
        float c = ws[OFF_C + mat * DD3 + tid];
        qkv[(mat * TB + 0) * DD3 + tid] = a0 + c;
        qkv[(mat * TB + 1) * DD3 + tid] = a1 + c;
    }
    __syncthreads();

    // ---- phase 3: polynomial sigmoid attention. Thread owns rows {ts, ts+192} of ONE token.
    {
        const f32x2 NEG1  = (f32x2){-1.0f, -1.0f};
        const f32x2 POS1  = (f32x2){ 1.0f,  1.0f};
        const f32x2 HALF2 = (f32x2){ 0.5f,  0.5f};
        const f32x2 PC1   = (f32x2){  1.4919730f,   1.4919730f};
        const f32x2 PC3   = (f32x2){ -4.1350490f,  -4.1350490f};
        const f32x2 PC5   = (f32x2){ 10.9501565f,  10.9501565f};
        const f32x2 PC7   = (f32x2){-20.0847165f, -20.0847165f};
        const f32x2 PC9   = (f32x2){ 22.6396415f,  22.6396415f};
        const f32x2 PC11  = (f32x2){-13.8982400f, -13.8982400f};
        const f32x2 PC13  = (f32x2){  3.5340290f,   3.5340290f};

        int t  = tid / 192;                 // wave-uniform (192 = 3 waves)
        int ts = tid - t * 192;
        const float* Qt = qkv + t * DD3;
        float fq0s = Qt[ts]       * (GAMMA_F / 6.0f);   // x = (gamma/6)*q*k, tanh(3x)
        float fq1s = Qt[ts + 192] * (GAMMA_F / 6.0f);
        f32x2 fq0 = (f32x2){fq0s, fq0s};
        f32x2 fq1 = (f32x2){fq1s, fq1s};
        const float4* K4 = (const float4*)(qkv + (TB + t) * DD3);
        const float4* V4 = (const float4*)(qkv + (2 * TB + t) * DD3);
        f32x2 rs0 = (f32x2){0.f, 0.f}, rs1 = (f32x2){0.f, 0.f};
        f32x2 av0 = (f32x2){0.f, 0.f}, av1 = (f32x2){0.f, 0.f};
        for (int j4 = 0; j4 < 96; ++j4) {
            float4 kk = K4[j4];
            float4 vv = V4[j4];
            f32x2 kxy = (f32x2){kk.x, kk.y}, kzw = (f32x2){kk.z, kk.w};
            f32x2 vxy = (f32x2){vv.x, vv.y}, vzw = (f32x2){vv.z, vv.w};
            PSIG(fq0, kxy, vxy, rs0, av0);
            PSIG(fq0, kzw, vzw, rs0, av0);
            PSIG(fq1, kxy, vxy, rs1, av1);
            PSIG(fq1, kzw, vzw, rs1, av1);
        }
        float rsum0 = rs0.x + rs0.y, rsum1 = rs1.x + rs1.y;
        float avs0  = av0.x + av0.y, avs1  = av1.x + av1.y;
        att[t * DD3 + ts]       = avs0 * __builtin_amdgcn_rcpf(rsum0 + 1e-8f);
        att[t * DD3 + ts + 192] = avs1 * __builtin_amdgcn_rcpf(rsum1 + 1e-8f);
    }
    __syncthreads();

    int wave = tid >> 6, lane64 = tid & 63;

    // ---- per-token sum of att (ln2 rank-1 fold)
    {
        float s0 = att[0 * DD3 + tid];
        float s1 = att[1 * DD3 + tid];
#pragma unroll
        for (int off = 32; off; off >>= 1) {
            s0 += __shfl_down(s0, off, 64);
            s1 += __shfl_down(s1, off, 64);
        }
        if (lane64 == 0) { red[wave] = s0; red[8 + wave] = s1; }
        __syncthreads();
        if (tid < TB) {
            float a = 0.f;
            for (int w = 0; w < 6; ++w) a += red[tid * 8 + w];
            ssum[tid] = a;
        }
        __syncthreads();
    }

    // ---- phase 4: h[t][o] = bp[o] + ln2*ssum[t] + sum_i att[t][i]*delta[i][o]
    const uint4* wp4 = (const uint4*)(ws + OFF_WP2);
    f32x2 acc2[3];
    {
        float bp0 = bp[tid], bp1 = bp[tid + DD3], bp2 = bp[tid + 2 * DD3];
        float b0 = LN2_F * ssum[0], b1 = LN2_F * ssum[1];
        acc2[0] = (f32x2){bp0 + b0, bp0 + b1};
        acc2[1] = (f32x2){bp1 + b0, bp1 + b1};
        acc2[2] = (f32x2){bp2 + b0, bp2 + b1};
    }
    const float4* att4 = (const float4*)att;
    for (int i4 = 0; i4 < 96; ++i4) {
        float4 a0 = att4[0 * 96 + i4];
        float4 a1 = att4[1 * 96 + i4];
        const float* af0 = (const float*)&a0;
        const float* af1 = (const float*)&a1;
#pragma unroll
        for (int e2 = 0; e2 < 2; ++e2) {
            uint4 u = wp4[(i4 * 2 + e2) * DD3 + tid];
            {
                float w0 = __uint_as_float(u.x << 16);
                float w1 = __uint_as_float(u.x & 0xffff0000u);
                float w2 = __uint_as_float(u.y << 16);
                f32x2 a01 = (f32x2){af0[e2 * 2], af1[e2 * 2]};
                acc2[0] = __builtin_elementwise_fma(a01, (f32x2){w0, w0}, acc2[0]);
                acc2[1] = __builtin_elementwise_fma(a01, (f32x2){w1, w1}, acc2[1]);
                acc2[2] = __builtin_elementwise_fma(a01, (f32x2){w2, w2}, acc2[2]);
            }
            {
                float w0 = __uint_as_float(u.z << 16);
                float w1 = __uint_as_float(u.z & 0xffff0000u);
                float w2 = __uint_as_float(u.w << 16);
                f32x2 a01 = (f32x2){af0[e2 * 2 + 1], af1[e2 * 2 + 1]};
                acc2[0] = __builtin_elementwise_fma(a01, (f32x2){w0, w0}, acc2[0]);
                acc2[1] = __builtin_elementwise_fma(a01, (f32x2){w1, w1}, acc2[1]);
                acc2[2] = __builtin_elementwise_fma(a01, (f32x2){w2, w2}, acc2[2]);
            }
        }
    }
    float av_[3][TB] = {{acc2[0].x, acc2[0].y}, {acc2[1].x, acc2[1].y}, {acc2[2].x, acc2[2].y}};

    // ---- phase 5: two-pass LayerNorm (mu first; then var of deviations)
#pragma unroll
    for (int t = 0; t < TB; ++t) {
        float s = av_[0][t] + av_[1][t] + av_[2][t];
#pragma unroll
        for (int off = 32; off; off >>= 1) s += __shfl_down(s, off, 64);
        if (lane64 == 0) red[t * 8 + wave] = s;
    }
    __syncthreads();
    if (tid < TB) {
        float a = 0.f;
        for (int w = 0; w < 6; ++w) a += red[tid * 8 + w];
        smu[tid] = a * (1.0f / 1152.0f);
    }
    __syncthreads();
#pragma unroll
    for (int t = 0; t < TB; ++t) {
        float mu = smu[t];
        av_[0][t] -= mu; av_[1][t] -= mu; av_[2][t] -= mu;
        float s = fmaf(av_[0][t], av_[0][t], fmaf(av_[1][t], av_[1][t], av_[2][t] * av_[2][t]));
#pragma unroll
        for (int off = 32; off; off >>= 1) s += __shfl_down(s, off, 64);
        if (lane64 == 0) red[t * 8 + wave] = s;
    }
    __syncthreads();
    if (tid < TB) {
        float b = 0.f;
        for (int w = 0; w < 6; ++w) b += red[tid * 8 + w];
        sinv[tid] = __builtin_amdgcn_rsqf(b * (1.0f / 1152.0f) + 1e-5f);
    }
    __syncthreads();
    float g0 = gn[tid], g1 = gn[tid + DD3], g2 = gn[tid + 2 * DD3];
    float b0 = bn[tid], b1 = bn[tid + DD3], b2 = bn[tid + 2 * DD3];
#pragma unroll
    for (int t = 0; t < TB; ++t) {
        float inv = sinv[t];
        size_t base = (size_t)(tok0 + t) * DD9;
        out[base + tid]           = fmaf(av_[0][t] * inv, g0, b0);
        out[base + tid + DD3]     = fmaf(av_[1][t] * inv, g1, b1);
        out[base + tid + 2 * DD3] = fmaf(av_[2][t] * inv, g2, b2);
    }
}

extern "C" void kernel_launch(void* const* d_in, const int* in_sizes, int n_in,
                              void* d_out, int out_size, void* d_ws, size_t ws_size,
                              hipStream_t stream) {
    const float* x  = (const float*)d_in[0];
    const float* Wq = (const float*)d_in[1];
    const float* bq = (const float*)d_in[2];
    const float* Sq = (const float*)d_in[3];
    const float* Wk = (const float*)d_in[4];
    const float* bk = (const float*)d_in[5];
    const float* Sk = (const float*)d_in[6];
    const float* Wv = (const float*)d_in[7];
    const float* bv = (const float*)d_in[8];
    const float* Sv = (const float*)d_in[9];
    const float* Wp = (const float*)d_in[10];
    const float* bp = (const float*)d_in[11];
    const float* gn = (const float*)d_in[12];
    const float* bn = (const float*)d_in[13];
    float* out = (float*)d_out;
    float* ws  = (float*)d_ws;

    hipLaunchKernelGGL(k_prep, dim3(771), dim3(384), 0, stream,
                       Wq, Wk, Wv, Wp, Sq, Sk, Sv, bq, bk, bv, ws);
    hipLaunchKernelGGL(k_fused, dim3(NTOK / TB), dim3(384), 0, stream, x, bp, gn, bn, ws, out);
}

// Round 13
// 148.506 us; speedup vs baseline: 1.1175x; 1.0523x over previous
//
#include <hip/hip_runtime.h>
#include <hip/hip_bf16.h>
#include <math.h>

// Problem geometry (B=2, T=1024, D=384 -> d=128, D3=384, D9=1152)
#define NTOK  2048
#define DD    128
#define DD3   384
#define DD9   1152
#define TB    2          // tokens per block in k_attn -> 1024 blocks
#define TBP   8          // tokens per block in k_proj -> 256 blocks
#define GAMMA_F 5.0f
#define LN2_F   0.69314718f

// Workspace layout (float units):
//  OFF_M   : Mq,Mk,Mv interleaved-by-4 (3 x 32x384 float4)
//  OFF_C   : cq,ck,cv (3 x 384 fp32)
//  OFF_BP  : B_pack bf16 [1152][384]: B[o][i] = bf16(softplus(Wp[o][i]) - ln2)
//  OFF_ATT : att bf16 [2048][384] (rounded attended values)
//  OFF_SSUM: per-token sum of ROUNDED att (fp32, 2048)
#define OFF_M    0
#define OFF_C    147456
#define OFF_BP   148608   // 221184 floats
#define OFF_ATT  369792   // 393216 floats (786432 ushort)
#define OFF_SSUM 763008   // 2048 floats

typedef __attribute__((ext_vector_type(2))) float f32x2;
typedef __attribute__((ext_vector_type(8))) short bf16x8;
typedef __attribute__((ext_vector_type(4))) float f32x4;

__device__ __forceinline__ float softplusf(float x) {
    return fmaxf(x, 0.0f) + log1pf(__expf(-fabsf(x)));   // stable log1p(exp(x))
}
__device__ __forceinline__ unsigned short f2bf(float f) {
    __hip_bfloat16 h = __float2bfloat16(f);              // RNE
    return *reinterpret_cast<unsigned short*>(&h);
}
__device__ __forceinline__ float bf2f(unsigned short u) {
    return __uint_as_float(((unsigned)u) << 16);
}

// ---------------- merged prep: grid 963 x 384
//  [0,576)   : B_pack natural [o][i] layout (coalesced both sides)
//  [576,960) : M matrices (interleaved-by-4, one (mat,i) per block)
//  [960,963) : c vectors
__global__ __launch_bounds__(384) void k_prep(const float* __restrict__ Wq, const float* __restrict__ Wk,
                                              const float* __restrict__ Wv, const float* __restrict__ Wp,
                                              const float* __restrict__ Sq, const float* __restrict__ Sk,
                                              const float* __restrict__ Sv, const float* __restrict__ bq,
                                              const float* __restrict__ bk, const float* __restrict__ bv,
                                              float* __restrict__ ws) {
    __shared__ float sw[DD3];
    int b = blockIdx.x, tid = threadIdx.x;
    if (b < 576) {                        // ---- B_pack: idx in [0, 221184)
        int idx = b * 384 + tid;
        unsigned lo = f2bf(softplusf(Wp[2 * idx + 0]) - LN2_F);
        unsigned hi = f2bf(softplusf(Wp[2 * idx + 1]) - LN2_F);
        ((unsigned*)(ws + OFF_BP))[idx] = lo | (hi << 16);
    } else if (b < 960) {                 // ---- M[i][m] for one (mat, i), interleaved store
        int bb = b - 576;
        int mat = bb >> 7, i = bb & 127;
        const float* W = (mat == 0) ? Wq : (mat == 1 ? Wk : Wv);
        const float* S = (mat == 0) ? Sq : (mat == 1 ? Sk : Sv);
        int m = tid;
        sw[m] = softplusf(W[m * DD + i]);                // j = tid
        __syncthreads();
        const float4* sw4 = (const float4*)sw;
        float a0 = 0.f, a1 = 0.f, a2 = 0.f, a3 = 0.f;
        for (int j4 = 0; j4 < 96; ++j4) {
            float4 w = sw4[j4];
            int j = j4 * 4;
            a0 = fmaf(w.x, S[(j + 0) * DD3 + m], a0);
            a1 = fmaf(w.y, S[(j + 1) * DD3 + m], a1);
            a2 = fmaf(w.z, S[(j + 2) * DD3 + m], a2);
            a3 = fmaf(w.w, S[(j + 3) * DD3 + m], a3);
        }
        ws[OFF_M + mat * 49152 + (i >> 2) * (DD3 * 4) + m * 4 + (i & 3)] = (a0 + a1) + (a2 + a3);
    } else {                              // ---- c[m]
        int mat = b - 960;
        const float* S = (mat == 0) ? Sq : (mat == 1 ? Sk : Sv);
        const float* bb_ = (mat == 0) ? bq : (mat == 1 ? bk : bv);
        int m = tid;
        float a0 = 0.f, a1 = 0.f, a2 = 0.f, a3 = 0.f;
        for (int j4 = 0; j4 < 96; ++j4) {
            int j = j4 * 4;
            a0 = fmaf(bb_[j + 0], S[(j + 0) * DD3 + m], a0);
            a1 = fmaf(bb_[j + 1], S[(j + 1) * DD3 + m], a1);
            a2 = fmaf(bb_[j + 2], S[(j + 2) * DD3 + m], a2);
            a3 = fmaf(bb_[j + 3], S[(j + 3) * DD3 + m], a3);
        }
        ws[OFF_C + mat * DD3 + m] = (a0 + a1) + (a2 + a3);
    }
}

// Deg-13 odd Chebyshev tanh(3x) poly (r12-proven, absmax 0.0176)
#define PSIG(FQ2, K2, V2, RS2, AV2) do {                                      \
        f32x2 x_ = __builtin_elementwise_min(                                  \
                     __builtin_elementwise_max((FQ2) * (K2), NEG1), POS1);     \
        f32x2 w_ = x_ * x_;                                                    \
        f32x2 p_ = __builtin_elementwise_fma(                                  \
                   __builtin_elementwise_fma(                                  \
                   __builtin_elementwise_fma(                                  \
                   __builtin_elementwise_fma(                                  \
                   __builtin_elementwise_fma(                                  \
                   __builtin_elementwise_fma(PC13, w_, PC11),                  \
                     w_, PC9), w_, PC7), w_, PC5), w_, PC3), w_, PC1);         \
        f32x2 s_ = __builtin_elementwise_fma(x_, p_, HALF2);                   \
        RS2 = RS2 + s_;                                                        \
        AV2 = __builtin_elementwise_fma(s_, (V2), AV2);                        \
    } while (0)

// ---------------- kernel A: QKV projection + sigmoid attention -> att(bf16), ssum
__global__ __launch_bounds__(384, 6) void k_attn(const float* __restrict__ x,
                                                 float* __restrict__ ws) {
    __shared__ float qkv[3 * TB * DD3];     // 9 KB
    __shared__ float att[TB * DD3];         // 3 KB (ROUNDED values, for ssum)
    __shared__ float red[16];

    int tid = threadIdx.x;                  // 0..383
    int tok0 = blockIdx.x * TB;
    const float* xb = x + (size_t)tok0 * DD3;

    // ---- phase 2: QKV projection (r10/r12-proven)
#pragma unroll
    for (int mat = 0; mat < 3; ++mat) {
        const float4* M4 = (const float4*)(ws + OFF_M + mat * 49152);
        const float* xt0 = xb + 0 * DD3 + mat * DD;
        const float* xt1 = xb + 1 * DD3 + mat * DD;
        float a0 = 0.f, a1 = 0.f;
        for (int i4 = 0; i4 < 32; ++i4) {
            float4 mm = M4[i4 * DD3 + tid];
            int i = i4 * 4;
            a0 = fmaf(xt0[i], mm.x, fmaf(xt0[i + 1], mm.y, fmaf(xt0[i + 2], mm.z, fmaf(xt0[i + 3], mm.w, a0))));
            a1 = fmaf(xt1[i], mm.x, fmaf(xt1[i + 1], mm.y, fmaf(xt1[i + 2], mm.z, fmaf(xt1[i + 3], mm.w, a1))));
        }
        float c = ws[OFF_C + mat * DD3 + tid];
        qkv[(mat * TB + 0) * DD3 + tid] = a0 + c;
        qkv[(mat * TB + 1) * DD3 + tid] = a1 + c;
    }
    __syncthreads();

    // ---- phase 3: polynomial sigmoid attention (r12-proven), then round to bf16.
    {
        const f32x2 NEG1  = (f32x2){-1.0f, -1.0f};
        const f32x2 POS1  = (f32x2){ 1.0f,  1.0f};
        const f32x2 HALF2 = (f32x2){ 0.5f,  0.5f};
        const f32x2 PC1   = (f32x2){  1.4919730f,   1.4919730f};
        const f32x2 PC3   = (f32x2){ -4.1350490f,  -4.1350490f};
        const f32x2 PC5   = (f32x2){ 10.9501565f,  10.9501565f};
        const f32x2 PC7   = (f32x2){-20.0847165f, -20.0847165f};
        const f32x2 PC9   = (f32x2){ 22.6396415f,  22.6396415f};
        const f32x2 PC11  = (f32x2){-13.8982400f, -13.8982400f};
        const f32x2 PC13  = (f32x2){  3.5340290f,   3.5340290f};

        int t  = tid / 192;
        int ts = tid - t * 192;
        const float* Qt = qkv + t * DD3;
        float fq0s = Qt[ts]       * (GAMMA_F / 6.0f);
        float fq1s = Qt[ts + 192] * (GAMMA_F / 6.0f);
        f32x2 fq0 = (f32x2){fq0s, fq0s};
        f32x2 fq1 = (f32x2){fq1s, fq1s};
        const float4* K4 = (const float4*)(qkv + (TB + t) * DD3);
        const float4* V4 = (const float4*)(qkv + (2 * TB + t) * DD3);
        f32x2 rs0 = (f32x2){0.f, 0.f}, rs1 = (f32x2){0.f, 0.f};
        f32x2 av0 = (f32x2){0.f, 0.f}, av1 = (f32x2){0.f, 0.f};
        for (int j4 = 0; j4 < 96; ++j4) {
            float4 kk = K4[j4];
            float4 vv = V4[j4];
            f32x2 kxy = (f32x2){kk.x, kk.y}, kzw = (f32x2){kk.z, kk.w};
            f32x2 vxy = (f32x2){vv.x, vv.y}, vzw = (f32x2){vv.z, vv.w};
            PSIG(fq0, kxy, vxy, rs0, av0);
            PSIG(fq0, kzw, vzw, rs0, av0);
            PSIG(fq1, kxy, vxy, rs1, av1);
            PSIG(fq1, kzw, vzw, rs1, av1);
        }
        float a0 = (av0.x + av0.y) * __builtin_amdgcn_rcpf(rs0.x + rs0.y + 1e-8f);
        float a1 = (av1.x + av1.y) * __builtin_amdgcn_rcpf(rs1.x + rs1.y + 1e-8f);
        // round ONCE; LDS keeps rounded fp32 so ssum matches what k_proj multiplies
        unsigned short b0 = f2bf(a0), b1 = f2bf(a1);
        att[t * DD3 + ts]       = bf2f(b0);
        att[t * DD3 + ts + 192] = bf2f(b1);
        unsigned short* ag = (unsigned short*)(ws + OFF_ATT);
        ag[(size_t)(tok0 + t) * DD3 + ts]       = b0;
        ag[(size_t)(tok0 + t) * DD3 + ts + 192] = b1;
    }
    __syncthreads();

    // ---- ssum over ROUNDED att (consistency with MFMA's bf16 operand)
    int wave = tid >> 6, lane64 = tid & 63;
    float s0 = att[0 * DD3 + tid];
    float s1 = att[1 * DD3 + tid];
#pragma unroll
    for (int off = 32; off; off >>= 1) {
        s0 += __shfl_down(s0, off, 64);
        s1 += __shfl_down(s1, off, 64);
    }
    if (lane64 == 0) { red[wave] = s0; red[8 + wave] = s1; }
    __syncthreads();
    if (tid < TB) {
        float a = 0.f;
        for (int w = 0; w < 6; ++w) a += red[tid * 8 + w];
        ws[OFF_SSUM + tok0 + tid] = a;
    }
}

// ---------------- kernel B: h = att(bf16) x delta(bf16) via MFMA + ln2 fold + LayerNorm
__global__ __launch_bounds__(384) void k_proj(const float* __restrict__ bp,
                                              const float* __restrict__ gn,
                                              const float* __restrict__ bn,
                                              const float* __restrict__ ws,
                                              float* __restrict__ out) {
    __shared__ unsigned short attb[16 * 392];   // 12.25 KB bf16 A-tile (rows 8..15 zero)
    __shared__ float h[TBP * DD9];              // 36 KB
    __shared__ float red[64];
    __shared__ float smu[TBP], sinv[TBP];

    int tid = threadIdx.x;
    int wave = tid >> 6, lane64 = tid & 63;
    int tok0 = blockIdx.x * TBP;

    // stage att rows 0..7 (coalesced b128) + zero rows 8..15
    {
        const unsigned short* ag = (const unsigned short*)(ws + OFF_ATT) + (size_t)tok0 * DD3;
        int r = tid / 48, c = (tid - r * 48) * 8;       // tid*8 = r*384 + c
        *(uint4*)(attb + r * 392 + c) = *(const uint4*)(ag + tid * 8);
        uint4 z; z.x = z.y = z.z = z.w = 0u;
        *(uint4*)(attb + (8 + r) * 392 + c) = z;
    }
    __syncthreads();

    // MFMA: wave owns 192 N-cols; 12 N-tiles x 12 K-steps, 16x16x32 bf16
    {
        int n0w  = wave * 192;
        int brow = lane64 & 15;
        int koff = (lane64 >> 4) * 8;
        const unsigned short* Bp = (const unsigned short*)(ws + OFF_BP);
        const unsigned short* abase = attb + brow * 392 + koff;
        const unsigned short* bbase = Bp + (size_t)(n0w + brow) * DD3 + koff;
        f32x4 acc[12];
#pragma unroll
        for (int nt = 0; nt < 12; ++nt) acc[nt] = (f32x4){0.f, 0.f, 0.f, 0.f};
        for (int ks = 0; ks < 12; ++ks) {
            bf16x8 a = *(const bf16x8*)(abase + ks * 32);
            const unsigned short* bk_ = bbase + ks * 32;
#pragma unroll
            for (int nt = 0; nt < 12; ++nt) {
                bf16x8 bfr = *(const bf16x8*)(bk_ + nt * 16 * DD3);
                acc[nt] = __builtin_amdgcn_mfma_f32_16x16x32_bf16(a, bfr, acc[nt], 0, 0, 0);
            }
        }
        // C/D: col = lane&15, row = (lane>>4)*4 + reg. Tokens = rows 0..7 -> lanes 0..31.
        if (lane64 < 32) {
            int rbase = (lane64 >> 4) * 4;
            int col0  = n0w + (lane64 & 15);
#pragma unroll
            for (int nt = 0; nt < 12; ++nt) {
#pragma unroll
                for (int r = 0; r < 4; ++r)
                    h[(rbase + r) * DD9 + col0 + nt * 16] = acc[nt][r];
            }
        }
    }
    __syncthreads();

    // bias + ln2*ssum fold, two-pass LayerNorm over 1152 per token
    const float* ssums = ws + OFF_SSUM + tok0;
    float acc3[3][TBP];
    {
        float bp0 = bp[tid], bp1 = bp[tid + DD3], bp2 = bp[tid + 2 * DD3];
#pragma unroll
        for (int t = 0; t < TBP; ++t) {
            float base = LN2_F * ssums[t];
            acc3[0][t] = h[t * DD9 + tid]           + bp0 + base;
            acc3[1][t] = h[t * DD9 + tid + DD3]     + bp1 + base;
            acc3[2][t] = h[t * DD9 + tid + 2 * DD3] + bp2 + base;
        }
    }
#pragma unroll
    for (int t = 0; t < TBP; ++t) {
        float s = acc3[0][t] + acc3[1][t] + acc3[2][t];
#pragma unroll
        for (int off = 32; off; off >>= 1) s += __shfl_down(s, off, 64);
        if (lane64 == 0) red[t * 8 + wave] = s;
    }
    __syncthreads();
    if (tid < TBP) {
        float a = 0.f;
        for (int w = 0; w < 6; ++w) a += red[tid * 8 + w];
        smu[tid] = a * (1.0f / 1152.0f);
    }
    __syncthreads();
#pragma unroll
    for (int t = 0; t < TBP; ++t) {
        float mu = smu[t];
        acc3[0][t] -= mu; acc3[1][t] -= mu; acc3[2][t] -= mu;
        float s = fmaf(acc3[0][t], acc3[0][t], fmaf(acc3[1][t], acc3[1][t], acc3[2][t] * acc3[2][t]));
#pragma unroll
        for (int off = 32; off; off >>= 1) s += __shfl_down(s, off, 64);
        if (lane64 == 0) red[t * 8 + wave] = s;
    }
    __syncthreads();
    if (tid < TBP) {
        float b = 0.f;
        for (int w = 0; w < 6; ++w) b += red[tid * 8 + w];
        sinv[tid] = __builtin_amdgcn_rsqf(b * (1.0f / 1152.0f) + 1e-5f);
    }
    __syncthreads();
    float g0 = gn[tid], g1 = gn[tid + DD3], g2 = gn[tid + 2 * DD3];
    float b0 = bn[tid], b1 = bn[tid + DD3], b2 = bn[tid + 2 * DD3];
#pragma unroll
    for (int t = 0; t < TBP; ++t) {
        float inv = sinv[t];
        size_t base = (size_t)(tok0 + t) * DD9;
        out[base + tid]           = fmaf(acc3[0][t] * inv, g0, b0);
        out[base + tid + DD3]     = fmaf(acc3[1][t] * inv, g1, b1);
        out[base + tid + 2 * DD3] = fmaf(acc3[2][t] * inv, g2, b2);
    }
}

extern "C" void kernel_launch(void* const* d_in, const int* in_sizes, int n_in,
                              void* d_out, int out_size, void* d_ws, size_t ws_size,
                              hipStream_t stream) {
    const float* x  = (const float*)d_in[0];
    const float* Wq = (const float*)d_in[1];
    const float* bq = (const float*)d_in[2];
    const float* Sq = (const float*)d_in[3];
    const float* Wk = (const float*)d_in[4];
    const float* bk = (const float*)d_in[5];
    const float* Sk = (const float*)d_in[6];
    const float* Wv = (const float*)d_in[7];
    const float* bv = (const float*)d_in[8];
    const float* Sv = (const float*)d_in[9];
    const float* Wp = (const float*)d_in[10];
    const float* bp = (const float*)d_in[11];
    const float* gn = (const float*)d_in[12];
    const float* bn = (const float*)d_in[13];
    float* out = (float*)d_out;
    float* ws  = (float*)d_ws;

    hipLaunchKernelGGL(k_prep, dim3(963), dim3(384), 0, stream,
                       Wq, Wk, Wv, Wp, Sq, Sk, Sv, bq, bk, bv, ws);
    hipLaunchKernelGGL(k_attn, dim3(NTOK / TB), dim3(384), 0, stream, x, ws);
    hipLaunchKernelGGL(k_proj, dim3(NTOK / TBP), dim3(384), 0, stream, bp, gn, bn, ws, out);
}